// Round 2
// baseline (365.881 us; speedup 1.0000x reference)
//
#include <hip/hip_runtime.h>

#define N_SERIES 2048
#define N_TIME 4096
#define SEAS 7
#define EMB 9
#define INPUT_SIZE 28
#define OUTPUT_SIZE 7

// sizes of the flat output chunks
#define OUT0_N (OUTPUT_SIZE * N_SERIES * INPUT_SIZE)   // 401408  windows_y_hat
#define OUT1_N (OUTPUT_SIZE * N_SERIES * OUTPUT_SIZE)  // 100352  windows_y (zeros)
#define LEV_N  (N_SERIES * N_TIME)                     // 8388608 levels
#define SEA_N  (N_SERIES * (N_TIME + SEAS))            // 8403968 seasonalities

// fast reciprocal: v_rcp_f32 + 1 Newton step -> ~0.5 ulp
__device__ __forceinline__ float rcp1(float x) {
    float r = __builtin_amdgcn_rcpf(x);
    r = fmaf(r, fmaf(-x, r, 1.0f), r);
    return r;
}

// One thread per series. 2048 threads = 32 waves; spread as 32 blocks of 64
// so each wave gets a CU's SIMD to itself (issue-rate bound loop).
__global__ __launch_bounds__(64) void es_scan(
    const float* __restrict__ y,
    const int* __restrict__ idxs,
    const float* __restrict__ emb,
    float* __restrict__ levels,
    float* __restrict__ seas_out)
{
    int s = blockIdx.x * 64 + threadIdx.x;   // grid is exactly 2048 threads
    const float* yr = y + (size_t)s * N_TIME;
    float* lr = levels + (size_t)s * N_TIME;
    float* sr = seas_out + (size_t)s * (N_TIME + SEAS);

    int idx = idxs[s];
    const float* e = emb + (size_t)idx * EMB;

    float lev_sms  = 1.0f / (1.0f + expf(-e[0]));
    float seas_sms = 1.0f / (1.0f + expf(-e[1]));
    float oml = 1.0f - lev_sms;
    float oms = 1.0f - seas_sms;

    // season ring buffer in registers; slot j holds season for t with t%7==j
    float sea[SEAS], rs[SEAS];
#pragma unroll
    for (int j = 0; j < SEAS; ++j) {
        float v = expf(e[2 + j]);
        sea[j] = v;
        rs[j]  = rcp1(v);
        sr[j]  = v;            // seasonalities[0..6] = init_seas
    }
    sr[SEAS] = sea[0];         // seasonalities[7] = init_seas[0]

    float level = yr[0] * rs[0];   // level0 = y[:,0] / init_seas[:,0]
    lr[0] = level;

    // t = 1 .. 4095, 4095 = 7*585; tb ≡ 1 (mod 7) so slot = (u+1)%7 is static
    for (int tb = 1; tb < N_TIME; tb += SEAS) {
#pragma unroll
        for (int u = 0; u < SEAS; ++u) {
            const int t = tb + u;
            const int slot = (u + 1) % SEAS;    // compile-time constant
            float yt = yr[t];
            // newlev = lev_sms*(y_t/season_t) + (1-lev_sms)*level
            float nl = fmaf(oml, level, lev_sms * (yt * rs[slot]));
            float rl = rcp1(nl);
            // newseason = seas_sms*(y_t/newlev) + (1-seas_sms)*season_t
            float ns = fmaf(oms, sea[slot], seas_sms * (yt * rl));
            sea[slot] = ns;
            rs[slot]  = rcp1(ns);
            lr[t] = nl;
            sr[t + SEAS] = ns;
            level = nl;
        }
    }
}

// windows_y_hat = log(y_win / lev_win / seas_win), transposed to (w, s, i);
// also zero windows_y. 501760 threads = 1960 * 256 exactly.
__global__ __launch_bounds__(256) void es_windows(
    const float* __restrict__ y,
    const float* __restrict__ levels,
    const float* __restrict__ seas,
    float* __restrict__ out0,
    float* __restrict__ out1)
{
    int tid = blockIdx.x * 256 + threadIdx.x;
    if (tid < OUT0_N) {
        int i = tid % INPUT_SIZE;
        int r = tid / INPUT_SIZE;
        int s = r % N_SERIES;
        int w = r / N_SERIES;
        int t = (N_TIME - INPUT_SIZE - OUTPUT_SIZE + 1) + w + i;   // 4062 + w + i
        float yt = y[(size_t)s * N_TIME + t];
        float lv = levels[(size_t)s * N_TIME + (N_TIME - OUTPUT_SIZE + w)]; // 4089+w
        float sv = seas[(size_t)s * (N_TIME + SEAS) + t];
        out0[tid] = logf(yt * rcp1(lv * sv));
    } else {
        int j = tid - OUT0_N;
        if (j < OUT1_N) out1[j] = 0.0f;
    }
}

extern "C" void kernel_launch(void* const* d_in, const int* in_sizes, int n_in,
                              void* d_out, int out_size, void* d_ws, size_t ws_size,
                              hipStream_t stream) {
    const float* y    = (const float*)d_in[0];
    const int*   idxs = (const int*)d_in[1];
    const float* emb  = (const float*)d_in[2];

    float* out  = (float*)d_out;
    float* out0 = out;                         // windows_y_hat
    float* out1 = out + OUT0_N;                // windows_y (zeros)
    float* lev  = out + OUT0_N + OUT1_N;       // levels
    float* sea  = out + OUT0_N + OUT1_N + LEV_N; // seasonalities

    es_scan<<<32, 64, 0, stream>>>(y, idxs, emb, lev, sea);
    es_windows<<<(OUT0_N + OUT1_N) / 256, 256, 0, stream>>>(y, lev, sea, out0, out1);
}

// Round 3
// 203.187 us; speedup vs baseline: 1.8007x; 1.8007x over previous
//
#include <hip/hip_runtime.h>

#define N_SERIES 2048
#define N_TIME 4096
#define SEAS 7
#define EMB 9
#define INPUT_SIZE 28
#define OUTPUT_SIZE 7

#define OUT0_N (OUTPUT_SIZE * N_SERIES * INPUT_SIZE)   // 401408  windows_y_hat
#define OUT1_N (OUTPUT_SIZE * N_SERIES * OUTPUT_SIZE)  // 100352  windows_y (zeros)
#define LEV_N  (N_SERIES * N_TIME)                     // 8388608 levels
#define SEA_N  (N_SERIES * (N_TIME + SEAS))            // 8403968 seasonalities

#define T_TILE 63      // multiple of 7 -> static season-ring slots; 63*65 = 4095
#define N_TILES 65
#define PAD 65         // padded series dim: (u+lane) % 32 -> 2-way max (free)

__device__ __forceinline__ float rcp_(float x) { return __builtin_amdgcn_rcpf(x); }

// 3 waves/block: wave0 scans (LDS+VALU only), wave1 prefetches y tile k+1
// (coalesced), wave2 stores lev/sea tile k-1 (coalesced). 64 series/block.
__global__ __launch_bounds__(192) void es_scan(
    const float* __restrict__ y,
    const int* __restrict__ idxs,
    const float* __restrict__ emb,
    float* __restrict__ levels,
    float* __restrict__ seas_out)
{
    __shared__ float ly[2][T_TILE][PAD];    // [buf][time][series]
    __shared__ float llev[2][T_TILE][PAD];
    __shared__ float lsea[2][T_TILE][PAD];

    const int lane = threadIdx.x & 63;
    const int wid  = threadIdx.x >> 6;
    const int s0   = blockIdx.x * 64;

    // scanner state (wave 0 only)
    float sea_r[SEAS], rsl[SEAS];
    float level = 0.f, oml = 0.f, oms = 0.f, lev_sms = 0.f, seas_sms = 0.f;

    if (wid == 0) {
        const int s = s0 + lane;
        const int idx = idxs[s];
        const float* e = emb + (size_t)idx * EMB;
        lev_sms  = 1.0f / (1.0f + expf(-e[0]));
        seas_sms = 1.0f / (1.0f + expf(-e[1]));
        oml = 1.0f - lev_sms;
        oms = 1.0f - seas_sms;
        float* sr = seas_out + (size_t)s * (N_TIME + SEAS);
#pragma unroll
        for (int j = 0; j < SEAS; ++j) {
            float v = expf(e[2 + j]);
            sea_r[j] = v;
            rsl[j] = lev_sms * rcp_(v);
            sr[j] = v;                       // seasonalities[0..6] = init
        }
        sr[SEAS] = sea_r[0];                 // seasonalities[7] = init[0]
        level = y[(size_t)s * N_TIME] * rcp_(sea_r[0]);
        levels[(size_t)s * N_TIME] = level;
    } else if (wid == 1) {
        // prologue: load tile 0 (t = 1..63) into buffer 0
#pragma unroll
        for (int r = 0; r < 64; ++r)
            if (lane < T_TILE)
                ly[0][lane][r] = y[(size_t)(s0 + r) * N_TIME + 1 + lane];
    }
    __syncthreads();

    for (int k = 0; k < N_TILES; ++k) {
        const int cur = k & 1;
        if (wid == 0) {
            // scan tile k: t = 1+63k .. 63+63k ; t%7 = (1+u)%7, static per j
            const float* lyc = &ly[cur][0][0];
            float* llc = &llev[cur][0][0];
            float* lsc = &lsea[cur][0][0];
            for (int g = 0; g < 9; ++g) {
#pragma unroll
                for (int j = 0; j < 7; ++j) {
                    const int u = g * 7 + j;
                    const int slot = (1 + j) % SEAS;   // == (1+u)%7, static
                    float yt = lyc[u * PAD + lane];
                    float nl = fmaf(oml, level, yt * rsl[slot]);
                    float rll = seas_sms * rcp_(nl);
                    float ns = fmaf(oms, sea_r[slot], yt * rll);
                    sea_r[slot] = ns;
                    rsl[slot] = lev_sms * rcp_(ns);
                    llc[u * PAD + lane] = nl;
                    lsc[u * PAD + lane] = ns;
                    level = nl;
                }
            }
        } else if (wid == 1) {
            // prefetch y tile k+1 into buffer cur^1 (coalesced row loads)
            if (k + 1 < N_TILES) {
                const int tn = 1 + (k + 1) * T_TILE;
                float tmp[64];
#pragma unroll
                for (int r = 0; r < 64; ++r)
                    tmp[r] = (lane < T_TILE)
                           ? y[(size_t)(s0 + r) * N_TIME + tn + lane] : 0.f;
#pragma unroll
                for (int r = 0; r < 64; ++r)
                    if (lane < T_TILE) ly[cur ^ 1][lane][r] = tmp[r];
            }
        } else {
            // store lev/sea tile k-1 from buffer cur^1 (coalesced row stores)
            if (k >= 1) {
                const int tp = 1 + (k - 1) * T_TILE;
                float tl[64], ts[64];
#pragma unroll
                for (int r = 0; r < 64; ++r) {
                    tl[r] = (lane < T_TILE) ? llev[cur ^ 1][lane][r] : 0.f;
                    ts[r] = (lane < T_TILE) ? lsea[cur ^ 1][lane][r] : 0.f;
                }
#pragma unroll
                for (int r = 0; r < 64; ++r) {
                    if (lane < T_TILE) {
                        const size_t s = s0 + r;
                        levels[s * N_TIME + tp + lane] = tl[r];
                        seas_out[s * (N_TIME + SEAS) + SEAS + tp + lane] = ts[r];
                    }
                }
            }
        }
        __syncthreads();
    }

    // epilogue: store tile 64 (in buffer 0); split rows across the 3 waves
    {
        const int tp = 1 + (N_TILES - 1) * T_TILE;       // 4033
        const int rbeg = wid * 22;
        const int rend = (rbeg + 22 < 64) ? rbeg + 22 : 64;
        for (int r = rbeg; r < rend; ++r) {
            if (lane < T_TILE) {
                const size_t s = s0 + r;
                levels[s * N_TIME + tp + lane] = llev[0][lane][r];
                seas_out[s * (N_TIME + SEAS) + SEAS + tp + lane] = lsea[0][lane][r];
            }
        }
    }
}

// windows_y_hat = log(y / lev / seas) transposed to (w, s, i); zero windows_y.
__global__ __launch_bounds__(256) void es_windows(
    const float* __restrict__ y,
    const float* __restrict__ levels,
    const float* __restrict__ seas,
    float* __restrict__ out0,
    float* __restrict__ out1)
{
    int tid = blockIdx.x * 256 + threadIdx.x;
    if (tid < OUT0_N) {
        int i = tid % INPUT_SIZE;
        int r = tid / INPUT_SIZE;
        int s = r & (N_SERIES - 1);
        int w = r >> 11;
        int t = (N_TIME - INPUT_SIZE - OUTPUT_SIZE + 1) + w + i;     // 4062+w+i
        float yt = y[(size_t)s * N_TIME + t];
        float lv = levels[(size_t)s * N_TIME + (N_TIME - OUTPUT_SIZE + w)];
        float sv = seas[(size_t)s * (N_TIME + SEAS) + t];
        // fast log: v_log_f32 (log2) * ln2; rcp err ~1e-7 — far under threshold
        float ratio = yt * rcp_(lv * sv);
        out0[tid] = __builtin_amdgcn_logf(ratio) * 0.6931471805599453f;
    } else {
        int j = tid - OUT0_N;
        if (j < OUT1_N) out1[j] = 0.0f;
    }
}

extern "C" void kernel_launch(void* const* d_in, const int* in_sizes, int n_in,
                              void* d_out, int out_size, void* d_ws, size_t ws_size,
                              hipStream_t stream) {
    const float* y    = (const float*)d_in[0];
    const int*   idxs = (const int*)d_in[1];
    const float* emb  = (const float*)d_in[2];

    float* out  = (float*)d_out;
    float* out0 = out;                           // windows_y_hat
    float* out1 = out + OUT0_N;                  // windows_y (zeros)
    float* lev  = out + OUT0_N + OUT1_N;         // levels
    float* sea  = out + OUT0_N + OUT1_N + LEV_N; // seasonalities

    es_scan<<<32, 192, 0, stream>>>(y, idxs, emb, lev, sea);
    es_windows<<<(OUT0_N + OUT1_N) / 256, 256, 0, stream>>>(y, lev, sea, out0, out1);
}